// Round 1
// baseline (987.716 us; speedup 1.0000x reference)
//
#include <hip/hip_runtime.h>

// Problem constants
#define Bn 2
#define Mn 25000
#define Nn 100000
#define Kn 16
#define MK (Mn*Kn)          // 400000 points per batch
#define GN_EPS 1e-5f
#define NEG_BIG (-3.402823466e+38f)

// ws layout (float offsets). First WS_ZERO_FLOATS are atomic accumulators (must be zeroed).
#define S1_OFF   0     // [2][4]   sums of x_c
#define S2_OFF   8     // [2][10]  upper-tri second moments of x
#define SH_OFF   32    // [2][64]  sum of h2 per channel
#define SQ_OFF   160   // [2][64]  sum of h2^2 per channel
#define WS_ZERO_FLOATS 288
#define A1_OFF   288   // [2][64]  gn1 scale
#define C1_OFF   416   // [2][64]  gn1 shift
#define BEFF_OFF 544   // [64]     effective bias for h2
#define A2_OFF   608   // [2][64]  gn2 scale
#define C2_OFF   736   // [2][64]  gn2 shift
#define WEFF_OFF 896   // [64*64]  at_w1 @ pe_w2
// total floats: 896 + 4096 = 4992  (~20 KB)

typedef float v2f __attribute__((ext_vector_type(2)));

__device__ __forceinline__ v2f v2fma(v2f a, v2f b, v2f c) {
    return __builtin_elementwise_fma(a, b, c);
}

// dot of a 64-float weight row (wave-uniform, 16B aligned) with a per-thread
// register vector held as 32 x v2f. Two independent packed-FMA chains.
__device__ __forceinline__ float dot64(const float* __restrict__ w, const v2f* r) {
    v2f acc0 = {0.f, 0.f}, acc1 = {0.f, 0.f};
#pragma unroll
    for (int c4 = 0; c4 < 16; ++c4) {
        const float4 wq = ((const float4*)w)[c4];
        v2f w0; w0.x = wq.x; w0.y = wq.y;
        v2f w1; w1.x = wq.z; w1.y = wq.w;
        acc0 = v2fma(w0, r[2*c4],     acc0);
        acc1 = v2fma(w1, r[2*c4 + 1], acc1);
    }
    const v2f acc = acc0 + acc1;
    return acc.x + acc.y;
}

// Compute local_pattern x[4] for point (b, i) then r1 = relu(a1*h1 + c1), h1 = W1 x + b1.
__device__ __forceinline__ void compute_r1v(
    int b, int i,
    const float* __restrict__ q, const float* __restrict__ kx,
    const int* __restrict__ idx,
    const float* __restrict__ w1, const float* __restrict__ b1,
    const float* __restrict__ a1, const float* __restrict__ c1,
    v2f* r1v)
{
    const int mm = i >> 4;
    const int id = idx[b*MK + i];
    const float qx = q[(b*3 + 0)*Mn + mm];
    const float qy = q[(b*3 + 1)*Mn + mm];
    const float qz = q[(b*3 + 2)*Mn + mm];
    const float ox = kx[(b*3 + 0)*Nn + id] - qx;
    const float oy = kx[(b*3 + 1)*Nn + id] - qy;
    const float oz = kx[(b*3 + 2)*Nn + id] - qz;
    const float d  = sqrtf(ox*ox + oy*oy + oz*oz);
    const float inv = 1.0f / fmaxf(d, 1e-12f);
    const float x0 = ox*inv, x1 = oy*inv, x2 = oz*inv, x3 = d;
#pragma unroll
    for (int o = 0; o < 64; ++o) {
        const float4 w = ((const float4*)w1)[o];
        float h = fmaf(w.x, x0, fmaf(w.y, x1, fmaf(w.z, x2, fmaf(w.w, x3, b1[o]))));
        h = fmaf(a1[o], h, c1[o]);
        h = fmaxf(h, 0.f);
        if (o & 1) r1v[o >> 1].y = h; else r1v[o >> 1].x = h;
    }
}

__device__ __forceinline__ float waveSum(float v) {
#pragma unroll
    for (int s = 32; s; s >>= 1) v += __shfl_down(v, s, 64);
    return v;
}

// ---------------- Kernel A: raw moments of local_pattern (per batch) ----------------
__global__ __launch_bounds__(256) void stats1_kernel(
    const float* __restrict__ q, const float* __restrict__ kx,
    const int* __restrict__ idx, float* __restrict__ ws)
{
    const int b = blockIdx.y;
    float s[4]  = {0.f, 0.f, 0.f, 0.f};
    float m2[10] = {0.f,0.f,0.f,0.f,0.f,0.f,0.f,0.f,0.f,0.f};
    for (int i = blockIdx.x*blockDim.x + threadIdx.x; i < MK; i += gridDim.x*blockDim.x) {
        const int mm = i >> 4;
        const int id = idx[b*MK + i];
        const float ox = kx[(b*3+0)*Nn + id] - q[(b*3+0)*Mn + mm];
        const float oy = kx[(b*3+1)*Nn + id] - q[(b*3+1)*Mn + mm];
        const float oz = kx[(b*3+2)*Nn + id] - q[(b*3+2)*Mn + mm];
        const float d  = sqrtf(ox*ox + oy*oy + oz*oz);
        const float inv = 1.0f / fmaxf(d, 1e-12f);
        const float x0 = ox*inv, x1 = oy*inv, x2 = oz*inv, x3 = d;
        s[0] += x0; s[1] += x1; s[2] += x2; s[3] += x3;
        m2[0] += x0*x0; m2[1] += x0*x1; m2[2] += x0*x2; m2[3] += x0*x3;
        m2[4] += x1*x1; m2[5] += x1*x2; m2[6] += x1*x3;
        m2[7] += x2*x2; m2[8] += x2*x3; m2[9] += x3*x3;
    }
#pragma unroll
    for (int j = 0; j < 4; ++j)  s[j]  = waveSum(s[j]);
#pragma unroll
    for (int j = 0; j < 10; ++j) m2[j] = waveSum(m2[j]);
    if ((threadIdx.x & 63) == 0) {
#pragma unroll
        for (int j = 0; j < 4; ++j)  atomicAdd(&ws[S1_OFF + b*4  + j], s[j]);
#pragma unroll
        for (int j = 0; j < 10; ++j) atomicAdd(&ws[S2_OFF + b*10 + j], m2[j]);
    }
}

// ---------------- Kernel B: gn1 affine coeffs + Weff/beff ----------------
__global__ void prep1_kernel(
    const float* __restrict__ ws_r,
    const float* __restrict__ w1, const float* __restrict__ b1,
    const float* __restrict__ g1, const float* __restrict__ be1,
    const float* __restrict__ w2, const float* __restrict__ pe_b2,
    const float* __restrict__ aw1, const float* __restrict__ ab1,
    float* __restrict__ ws)
{
    __shared__ float Eh[2][64], Eq[2][64];
    const int t = threadIdx.x;
    if (t < 128) {
        const int b = t >> 6, o = t & 63;
        const double inv = 1.0 / (double)MK;
        double mu[4];
#pragma unroll
        for (int c = 0; c < 4; ++c) mu[c] = (double)ws_r[S1_OFF + b*4 + c] * inv;
        // expand 10 upper-tri entries to full 4x4
        double m2[4][4];
        {
            const int map[4][4] = {{0,1,2,3},{1,4,5,6},{2,5,7,8},{3,6,8,9}};
#pragma unroll
            for (int c = 0; c < 4; ++c)
#pragma unroll
                for (int c2 = 0; c2 < 4; ++c2)
                    m2[c][c2] = (double)ws_r[S2_OFF + b*10 + map[c][c2]] * inv;
        }
        double w[4];
#pragma unroll
        for (int c = 0; c < 4; ++c) w[c] = (double)w1[o*4 + c];
        double s = 0.0, qd = 0.0;
#pragma unroll
        for (int c = 0; c < 4; ++c) {
            s += w[c] * mu[c];
#pragma unroll
            for (int c2 = 0; c2 < 4; ++c2) qd += w[c]*w[c2]*m2[c][c2];
        }
        const double bb = (double)b1[o];
        Eh[b][o] = (float)(s + bb);
        Eq[b][o] = (float)(qd + 2.0*bb*s + bb*bb);
    }
    __syncthreads();
    if (t < 128) {
        const int b = t >> 6, o = t & 63, g = o & ~7;
        float mg = 0.f, qg = 0.f;
#pragma unroll
        for (int j = 0; j < 8; ++j) { mg += Eh[b][g + j]; qg += Eq[b][g + j]; }
        mg *= 0.125f; qg *= 0.125f;
        const float var = fmaxf(qg - mg*mg, 0.f);
        const float a = g1[o] / sqrtf(var + GN_EPS);
        ws[A1_OFF + b*64 + o] = a;
        ws[C1_OFF + b*64 + o] = be1[o] - mg*a;
    }
    // Weff = at_w1 @ pe_w2 ;  beff = at_w1 @ pe_b2 + at_b1
    for (int e = t; e < 4096; e += blockDim.x) {
        const int o = e >> 6, c = e & 63;
        float acc = 0.f;
        for (int d = 0; d < 64; ++d) acc = fmaf(aw1[o*64 + d], w2[d*64 + c], acc);
        ws[WEFF_OFF + e] = acc;
    }
    if (t < 64) {
        float acc = ab1[t];
        for (int d = 0; d < 64; ++d) acc = fmaf(aw1[t*64 + d], pe_b2[d], acc);
        ws[BEFF_OFF + t] = acc;
    }
}

// ---------------- Kernel C: per-channel h2 sums (h2 = Weff @ r1 + beff) ----------------
__global__ __launch_bounds__(256) void pass2_kernel(
    const float* __restrict__ q, const float* __restrict__ kx,
    const int* __restrict__ idx,
    const float* __restrict__ w1, const float* __restrict__ b1,
    const float* __restrict__ cws,   // read-only view of ws
    float* __restrict__ ws)          // atomic accumulators (disjoint region)
{
    const int b = blockIdx.y;
    const float* a1   = cws + A1_OFF + (b << 6);
    const float* c1   = cws + C1_OFF + (b << 6);
    const float* Weff = cws + WEFF_OFF;
    const float* beff = cws + BEFF_OFF;

    float sh[64], sq[64];
#pragma unroll
    for (int o = 0; o < 64; ++o) { sh[o] = 0.f; sq[o] = 0.f; }

    for (int i = blockIdx.x*blockDim.x + threadIdx.x; i < MK; i += gridDim.x*blockDim.x) {
        v2f r1v[32];
        compute_r1v(b, i, q, kx, idx, w1, b1, a1, c1, r1v);
#pragma unroll
        for (int o = 0; o < 64; ++o) {
            const float h = beff[o] + dot64(Weff + (o << 6), r1v);
            sh[o] += h;
            sq[o] = fmaf(h, h, sq[o]);
        }
    }

    __shared__ float red[4][128];
    const int lane = threadIdx.x & 63, wv = threadIdx.x >> 6;
#pragma unroll
    for (int o = 0; o < 64; ++o) {
        const float vs = waveSum(sh[o]);
        const float vq = waveSum(sq[o]);
        if (lane == 0) { red[wv][o] = vs; red[wv][64 + o] = vq; }
    }
    __syncthreads();
    if (threadIdx.x < 128) {
        const float tsum = red[0][threadIdx.x] + red[1][threadIdx.x]
                         + red[2][threadIdx.x] + red[3][threadIdx.x];
        if (threadIdx.x < 64) atomicAdd(&ws[SH_OFF + b*64 + threadIdx.x], tsum);
        else                  atomicAdd(&ws[SQ_OFF + b*64 + (threadIdx.x - 64)], tsum);
    }
}

// ---------------- Kernel D: gn2 affine coeffs ----------------
__global__ void prep2_kernel(
    const float* __restrict__ ws_r,
    const float* __restrict__ g2, const float* __restrict__ be2,
    float* __restrict__ ws)
{
    const int t = threadIdx.x;
    if (t >= 128) return;
    const int b = t >> 6, o = t & 63, g = o & ~7;
    const double inv = 1.0 / (8.0 * (double)MK);
    double mg = 0.0, qg = 0.0;
#pragma unroll
    for (int j = 0; j < 8; ++j) {
        mg += (double)ws_r[SH_OFF + b*64 + g + j];
        qg += (double)ws_r[SQ_OFF + b*64 + g + j];
    }
    mg *= inv; qg *= inv;
    const float var = fmaxf((float)(qg - mg*mg), 0.f);
    const float a = g2[o] / sqrtf(var + GN_EPS);
    ws[A2_OFF + b*64 + o] = a;
    ws[C2_OFF + b*64 + o] = be2[o] - (float)mg * a;
}

// ---------------- Kernel E: full forward + masked softmax + output ----------------
__global__ __launch_bounds__(256) void pass3_kernel(
    const float* __restrict__ q, const float* __restrict__ kx,
    const int* __restrict__ idx, const int* __restrict__ mask,
    const float* __restrict__ w1,  const float* __restrict__ b1,
    const float* __restrict__ w2,  const float* __restrict__ b2,
    const float* __restrict__ aw1, const float* __restrict__ ab1,
    const float* __restrict__ aw2, const float* __restrict__ ab2,
    const float* __restrict__ cws, float* __restrict__ out)
{
    const int b = blockIdx.y;
    const int i = blockIdx.x*blockDim.x + threadIdx.x;
    if (i >= MK) return;            // tail: whole 16-lane k-groups exit together
    const int mm = i >> 4, kk = i & 15;

    const float* a1 = cws + A1_OFF + (b << 6);
    const float* c1 = cws + C1_OFF + (b << 6);
    const float* a2 = cws + A2_OFF + (b << 6);
    const float* c2 = cws + C2_OFF + (b << 6);

    v2f r1v[32];
    compute_r1v(b, i, q, kx, idx, w1, b1, a1, c1, r1v);

    // pe = pe_w2 @ r1 + pe_b2
    v2f pev[32];
#pragma unroll
    for (int o = 0; o < 64; ++o) {
        const float v = b2[o] + dot64(w2 + (o << 6), r1v);
        if (o & 1) pev[o >> 1].y = v; else pev[o >> 1].x = v;
    }
    // r2 = relu(a2 * (at_w1 @ pe + at_b1) + c2)
    v2f r2v[32];
#pragma unroll
    for (int o = 0; o < 64; ++o) {
        float h = ab1[o] + dot64(aw1 + (o << 6), pev);
        h = fmaf(a2[o], h, c2[o]);
        h = fmaxf(h, 0.f);
        if (o & 1) r2v[o >> 1].y = h; else r2v[o >> 1].x = h;
    }

    const bool live = (mask[b*MK + i] != 0);
    float* outp = out + (size_t)(b << 6) * Mn + mm;

#pragma unroll
    for (int o = 0; o < 64; ++o) {
        float l = ab2[o] + dot64(aw2 + (o << 6), r2v);
        l = live ? l : NEG_BIG;
        float mx = l;
#pragma unroll
        for (int s = 8; s; s >>= 1) mx = fmaxf(mx, __shfl_xor(mx, s, 16));
        const float e = __expf(l - mx);
        const float pe_o = (o & 1) ? pev[o >> 1].y : pev[o >> 1].x;
        float se = e, sw = pe_o * e;
#pragma unroll
        for (int s = 8; s; s >>= 1) { se += __shfl_xor(se, s, 16); sw += __shfl_xor(sw, s, 16); }
        if (kk == 0) outp[(size_t)o * Mn] = sw / se;
    }
}

extern "C" void kernel_launch(void* const* d_in, const int* in_sizes, int n_in,
                              void* d_out, int out_size, void* d_ws, size_t ws_size,
                              hipStream_t stream) {
    (void)in_sizes; (void)n_in; (void)out_size; (void)ws_size;
    const float* q    = (const float*)d_in[0];
    const float* kx   = (const float*)d_in[1];
    const int*   idx  = (const int*)  d_in[2];
    const int*   mask = (const int*)  d_in[3];
    const float* w1   = (const float*)d_in[4];
    const float* b1   = (const float*)d_in[5];
    const float* g1   = (const float*)d_in[6];
    const float* be1  = (const float*)d_in[7];
    const float* w2   = (const float*)d_in[8];
    const float* b2   = (const float*)d_in[9];
    const float* aw1  = (const float*)d_in[10];
    const float* ab1  = (const float*)d_in[11];
    const float* g2   = (const float*)d_in[12];
    const float* be2  = (const float*)d_in[13];
    const float* aw2  = (const float*)d_in[14];
    const float* ab2  = (const float*)d_in[15];
    float* out = (float*)d_out;
    float* ws  = (float*)d_ws;

    hipMemsetAsync(ws, 0, WS_ZERO_FLOATS * sizeof(float), stream);

    dim3 gA(128, Bn);
    stats1_kernel<<<gA, 256, 0, stream>>>(q, kx, idx, ws);

    prep1_kernel<<<1, 256, 0, stream>>>(ws, w1, b1, g1, be1, w2, b2, aw1, ab1, ws);

    dim3 gC(256, Bn);
    pass2_kernel<<<gC, 256, 0, stream>>>(q, kx, idx, w1, b1, ws, ws);

    prep2_kernel<<<1, 128, 0, stream>>>(ws, g2, be2, ws);

    dim3 gE((MK + 255) / 256, Bn);
    pass3_kernel<<<gE, 256, 0, stream>>>(q, kx, idx, mask, w1, b1, w2, b2,
                                         aw1, ab1, aw2, ab2, ws, out);
}

// Round 2
// 738.337 us; speedup vs baseline: 1.3378x; 1.3378x over previous
//
#include <hip/hip_runtime.h>

// Problem constants
#define Bn 2
#define Mn 25000
#define Nn 100000
#define Kn 16
#define MK (Mn*Kn)          // 400000 points per batch
#define GN_EPS 1e-5f
#define NEG_BIG (-3.402823466e+38f)

// ws layout (float offsets). First WS_ZERO_FLOATS are atomic accumulators (zeroed).
#define S1_OFF   0      // [2][4]    sums of x_c
#define S2_OFF   8      // [2][10]   upper-tri second moments of x
#define ER1_OFF  32     // [2][64]   sum of r1 per channel
#define GRAM_OFF 160    // [2][4096] Gram of r1
#define WS_ZERO_FLOATS 8352
#define A1_OFF   8352   // [2][64] gn1 scale
#define C1_OFF   8480   // [2][64] gn1 shift
#define A2_OFF   8608   // [2][64] gn2 scale
#define C2_OFF   8736   // [2][64] gn2 shift
#define BEFF_OFF 8864   // [64]    effective bias for h2
#define WEFF_OFF 8928   // [64*64] at_w1 @ pe_w2
// total floats: 13024 (~52 KB)

typedef float v2f __attribute__((ext_vector_type(2)));
typedef _Float16 hf8 __attribute__((ext_vector_type(8)));
typedef _Float16 hf4 __attribute__((ext_vector_type(4)));
typedef float f32x16 __attribute__((ext_vector_type(16)));

__device__ __forceinline__ f32x16 mfma16(hf8 a, hf8 b, f32x16 c) {
    return __builtin_amdgcn_mfma_f32_32x32x16_f16(a, b, c, 0, 0, 0);
}
__device__ __forceinline__ f32x16 splat16(float v) {
    f32x16 x;
#pragma unroll
    for (int r = 0; r < 16; ++r) x[r] = v;
    return x;
}

// Compute local_pattern x[4] for point (b,i) then r1 = relu(a1*h1 + c1), h1 = W1 x + b1.
__device__ __forceinline__ void compute_r1v(
    int b, int i,
    const float* __restrict__ q, const float* __restrict__ kx,
    const int* __restrict__ idx,
    const float* __restrict__ w1, const float* __restrict__ b1,
    const float* __restrict__ a1, const float* __restrict__ c1,
    v2f* r1v)
{
    const int mm = i >> 4;
    const int id = idx[b*MK + i];
    const float qx = q[(b*3 + 0)*Mn + mm];
    const float qy = q[(b*3 + 1)*Mn + mm];
    const float qz = q[(b*3 + 2)*Mn + mm];
    const float ox = kx[(b*3 + 0)*Nn + id] - qx;
    const float oy = kx[(b*3 + 1)*Nn + id] - qy;
    const float oz = kx[(b*3 + 2)*Nn + id] - qz;
    const float d  = sqrtf(ox*ox + oy*oy + oz*oz);
    const float inv = 1.0f / fmaxf(d, 1e-12f);
    const float x0 = ox*inv, x1 = oy*inv, x2 = oz*inv, x3 = d;
#pragma unroll
    for (int o = 0; o < 64; ++o) {
        const float4 w = ((const float4*)w1)[o];
        float h = fmaf(w.x, x0, fmaf(w.y, x1, fmaf(w.z, x2, fmaf(w.w, x3, b1[o]))));
        h = fmaf(a1[o], h, c1[o]);
        h = fmaxf(h, 0.f);
        if (o & 1) r1v[o >> 1].y = h; else r1v[o >> 1].x = h;
    }
}

__device__ __forceinline__ float waveSum(float v) {
#pragma unroll
    for (int s = 32; s; s >>= 1) v += __shfl_down(v, s, 64);
    return v;
}

// ---------------- Kernel A: raw moments of local_pattern (per batch) ----------------
__global__ __launch_bounds__(256) void stats1_kernel(
    const float* __restrict__ q, const float* __restrict__ kx,
    const int* __restrict__ idx, float* __restrict__ ws)
{
    const int b = blockIdx.y;
    float s[4]  = {0.f, 0.f, 0.f, 0.f};
    float m2[10] = {0.f,0.f,0.f,0.f,0.f,0.f,0.f,0.f,0.f,0.f};
    for (int i = blockIdx.x*blockDim.x + threadIdx.x; i < MK; i += gridDim.x*blockDim.x) {
        const int mm = i >> 4;
        const int id = idx[b*MK + i];
        const float ox = kx[(b*3+0)*Nn + id] - q[(b*3+0)*Mn + mm];
        const float oy = kx[(b*3+1)*Nn + id] - q[(b*3+1)*Mn + mm];
        const float oz = kx[(b*3+2)*Nn + id] - q[(b*3+2)*Mn + mm];
        const float d  = sqrtf(ox*ox + oy*oy + oz*oz);
        const float inv = 1.0f / fmaxf(d, 1e-12f);
        const float x0 = ox*inv, x1 = oy*inv, x2 = oz*inv, x3 = d;
        s[0] += x0; s[1] += x1; s[2] += x2; s[3] += x3;
        m2[0] += x0*x0; m2[1] += x0*x1; m2[2] += x0*x2; m2[3] += x0*x3;
        m2[4] += x1*x1; m2[5] += x1*x2; m2[6] += x1*x3;
        m2[7] += x2*x2; m2[8] += x2*x3; m2[9] += x3*x3;
    }
#pragma unroll
    for (int j = 0; j < 4; ++j)  s[j]  = waveSum(s[j]);
#pragma unroll
    for (int j = 0; j < 10; ++j) m2[j] = waveSum(m2[j]);
    if ((threadIdx.x & 63) == 0) {
#pragma unroll
        for (int j = 0; j < 4; ++j)  atomicAdd(&ws[S1_OFF + b*4  + j], s[j]);
#pragma unroll
        for (int j = 0; j < 10; ++j) atomicAdd(&ws[S2_OFF + b*10 + j], m2[j]);
    }
}

// ---------------- Kernel B: gn1 affine coeffs + Weff/beff ----------------
__global__ void prep1_kernel(
    const float* __restrict__ ws_r,
    const float* __restrict__ w1, const float* __restrict__ b1,
    const float* __restrict__ g1, const float* __restrict__ be1,
    const float* __restrict__ w2, const float* __restrict__ pe_b2,
    const float* __restrict__ aw1, const float* __restrict__ ab1,
    float* __restrict__ ws)
{
    __shared__ float Eh[2][64], Eq[2][64];
    const int t = threadIdx.x;
    if (t < 128) {
        const int b = t >> 6, o = t & 63;
        const double inv = 1.0 / (double)MK;
        double mu[4];
#pragma unroll
        for (int c = 0; c < 4; ++c) mu[c] = (double)ws_r[S1_OFF + b*4 + c] * inv;
        double m2[4][4];
        {
            const int map[4][4] = {{0,1,2,3},{1,4,5,6},{2,5,7,8},{3,6,8,9}};
#pragma unroll
            for (int c = 0; c < 4; ++c)
#pragma unroll
                for (int c2 = 0; c2 < 4; ++c2)
                    m2[c][c2] = (double)ws_r[S2_OFF + b*10 + map[c][c2]] * inv;
        }
        double w[4];
#pragma unroll
        for (int c = 0; c < 4; ++c) w[c] = (double)w1[o*4 + c];
        double s = 0.0, qd = 0.0;
#pragma unroll
        for (int c = 0; c < 4; ++c) {
            s += w[c] * mu[c];
#pragma unroll
            for (int c2 = 0; c2 < 4; ++c2) qd += w[c]*w[c2]*m2[c][c2];
        }
        const double bb = (double)b1[o];
        Eh[b][o] = (float)(s + bb);
        Eq[b][o] = (float)(qd + 2.0*bb*s + bb*bb);
    }
    __syncthreads();
    if (t < 128) {
        const int b = t >> 6, o = t & 63, g = o & ~7;
        float mg = 0.f, qg = 0.f;
#pragma unroll
        for (int j = 0; j < 8; ++j) { mg += Eh[b][g + j]; qg += Eq[b][g + j]; }
        mg *= 0.125f; qg *= 0.125f;
        const float var = fmaxf(qg - mg*mg, 0.f);
        const float a = g1[o] / sqrtf(var + GN_EPS);
        ws[A1_OFF + b*64 + o] = a;
        ws[C1_OFF + b*64 + o] = be1[o] - mg*a;
    }
    // Weff = at_w1 @ pe_w2 ;  beff = at_w1 @ pe_b2 + at_b1
    for (int e = t; e < 4096; e += blockDim.x) {
        const int o = e >> 6, c = e & 63;
        float acc = 0.f;
        for (int d = 0; d < 64; ++d) acc = fmaf(aw1[o*64 + d], w2[d*64 + c], acc);
        ws[WEFF_OFF + e] = acc;
    }
    if (t < 64) {
        float acc = ab1[t];
        for (int d = 0; d < 64; ++d) acc = fmaf(aw1[t*64 + d], pe_b2[d], acc);
        ws[BEFF_OFF + t] = acc;
    }
}

// ---------------- Kernel C: r1 sums + Gram(r1) via MFMA ----------------
__global__ __launch_bounds__(256, 2) void pass2_kernel(
    const float* __restrict__ q, const float* __restrict__ kx,
    const int* __restrict__ idx,
    const float* __restrict__ w1, const float* __restrict__ b1,
    const float* __restrict__ cws, float* __restrict__ ws)
{
    __shared__ __align__(16) _Float16 XT[64][264];   // [ch][pt], padded
    const int b = blockIdx.y;
    const int tid = threadIdx.x, lane = tid & 63, wv = tid >> 6;
    const float* a1 = cws + A1_OFF + (b << 6);
    const float* c1 = cws + C1_OFF + (b << 6);

    v2f sums[32];
#pragma unroll
    for (int c = 0; c < 32; ++c) { sums[c].x = 0.f; sums[c].y = 0.f; }
    f32x16 acc = splat16(0.f);

    const int i0 = 32*(wv >> 1), j0 = 32*(wv & 1);
    const int rowA = i0 + (lane & 31), rowB = j0 + (lane & 31);
    const int klo = (lane >> 5) * 8;

    for (int base = blockIdx.x * 256; base < MK; base += gridDim.x * 256) {
        const int i = base + tid;
        v2f r1v[32];
        if (i < MK) {
            compute_r1v(b, i, q, kx, idx, w1, b1, a1, c1, r1v);
        } else {
#pragma unroll
            for (int c = 0; c < 32; ++c) { r1v[c].x = 0.f; r1v[c].y = 0.f; }
        }
#pragma unroll
        for (int c = 0; c < 32; ++c) sums[c] += r1v[c];
#pragma unroll
        for (int o2 = 0; o2 < 32; ++o2) {
            XT[2*o2    ][tid] = (_Float16)r1v[o2].x;
            XT[2*o2 + 1][tid] = (_Float16)r1v[o2].y;
        }
        __syncthreads();
#pragma unroll
        for (int ks = 0; ks < 16; ++ks) {
            hf8 af = *(const hf8*)&XT[rowA][16*ks + klo];
            hf8 bf = *(const hf8*)&XT[rowB][16*ks + klo];
            acc = mfma16(af, bf, acc);
        }
        __syncthreads();
    }
#pragma unroll
    for (int o = 0; o < 64; ++o) {
        float s = (o & 1) ? sums[o >> 1].y : sums[o >> 1].x;
        s = waveSum(s);
        if (lane == 0) atomicAdd(&ws[ER1_OFF + b*64 + o], s);
    }
#pragma unroll
    for (int r = 0; r < 16; ++r) {
        const int gi = i0 + (r & 3) + 8*(r >> 2) + 4*(lane >> 5);
        const int gj = j0 + (lane & 31);
        atomicAdd(&ws[GRAM_OFF + b*4096 + gi*64 + gj], acc[r]);
    }
}

// ---------------- Kernel D: gn2 affine coeffs from Gram ----------------
__global__ void prep2_kernel(const float* __restrict__ ws_r,
                             const float* __restrict__ g2, const float* __restrict__ be2,
                             float* __restrict__ ws)
{
    __shared__ float EH[2][64], EQ[2][64];
    const int t = threadIdx.x;
    if (t < 128) {
        const int b = t >> 6, o = t & 63;
        const float* Wo = ws_r + WEFF_OFF + o*64;
        const double beff = (double)ws_r[BEFF_OFF + o];
        const double invMK = 1.0 / (double)MK;
        double dot = 0.0;
        for (int c = 0; c < 64; ++c)
            dot += (double)Wo[c] * (double)ws_r[ER1_OFF + b*64 + c];
        dot *= invMK;
        double quad = 0.0;
        for (int c = 0; c < 64; ++c) {
            double rowacc = 0.0;
            const float* Gr = ws_r + GRAM_OFF + b*4096 + c*64;
            for (int c2 = 0; c2 < 64; ++c2)
                rowacc += (double)Gr[c2] * (double)Wo[c2];
            quad += (double)Wo[c] * rowacc;
        }
        quad *= invMK;
        EH[b][o] = (float)(dot + beff);
        EQ[b][o] = (float)(quad + 2.0*beff*dot + beff*beff);
    }
    __syncthreads();
    if (t < 128) {
        const int b = t >> 6, o = t & 63, g = o & ~7;
        float mg = 0.f, qg = 0.f;
#pragma unroll
        for (int j = 0; j < 8; ++j) { mg += EH[b][g + j]; qg += EQ[b][g + j]; }
        mg *= 0.125f; qg *= 0.125f;
        const float var = fmaxf(qg - mg*mg, 0.f);
        const float a = g2[o] / sqrtf(var + GN_EPS);
        ws[A2_OFF + b*64 + o] = a;
        ws[C2_OFF + b*64 + o] = be2[o] - mg*a;
    }
}

// ---------------- Kernel E: fused MFMA forward + masked softmax + output ----------------
__global__ __launch_bounds__(256, 2) void pass3_kernel(
    const float* __restrict__ q, const float* __restrict__ kx,
    const int* __restrict__ idx, const int* __restrict__ mask,
    const float* __restrict__ w1,  const float* __restrict__ b1,
    const float* __restrict__ w2,  const float* __restrict__ b2,
    const float* __restrict__ aw1, const float* __restrict__ ab1,
    const float* __restrict__ aw2, const float* __restrict__ ab2,
    const float* __restrict__ cws, float* __restrict__ out)
{
    __shared__ __align__(16) _Float16 X[256][72];     // activations (reused per layer)
    __shared__ __align__(16) _Float16 W[3][64][72];   // w2 / aw1 / aw2 as f16
    __shared__ float O[64][20];                       // output staging [o][m_local]

    const int b = blockIdx.y;
    const int base = blockIdx.x * 256;
    const int tid = threadIdx.x;
    const int lane = tid & 63, wv = tid >> 6;
    const int colA = lane & 31;
    const int klo = (lane >> 5) * 8;

    for (int e = tid; e < 4096; e += 256) {
        const int o = e >> 6, c = e & 63;
        W[0][o][c] = (_Float16)w2[e];
        W[1][o][c] = (_Float16)aw1[e];
        W[2][o][c] = (_Float16)aw2[e];
    }

    const int i = base + tid;
    {
        v2f r1v[32];
        if (i < MK) {
            compute_r1v(b, i, q, kx, idx, w1, b1,
                        cws + A1_OFF + (b << 6), cws + C1_OFF + (b << 6), r1v);
        } else {
#pragma unroll
            for (int c = 0; c < 32; ++c) { r1v[c].x = 0.f; r1v[c].y = 0.f; }
        }
#pragma unroll
        for (int c4 = 0; c4 < 16; ++c4) {
            hf4 t;
            t[0] = (_Float16)r1v[2*c4].x;     t[1] = (_Float16)r1v[2*c4].y;
            t[2] = (_Float16)r1v[2*c4 + 1].x; t[3] = (_Float16)r1v[2*c4 + 1].y;
            *(hf4*)&X[tid][4*c4] = t;
        }
    }
    const bool live = (i < MK) && (mask[(size_t)b*MK + i] != 0);
    const unsigned long long mbits = __ballot(live);   // lane l <-> pt 64*wv + l

    __syncthreads();

    const int p0 = 2*wv, p1 = 2*wv + 1;

    // ---- GEMM1: pe = r1 @ w2^T + b2 ----
    f32x16 pe00 = splat16(b2[colA]);
    f32x16 pe01 = splat16(b2[32 + colA]);
    f32x16 pe10 = pe00, pe11 = pe01;
#pragma unroll
    for (int ks = 0; ks < 4; ++ks) {
        const int off = 16*ks + klo;
        hf8 a0  = *(const hf8*)&X[32*p0 + colA][off];
        hf8 a1  = *(const hf8*)&X[32*p1 + colA][off];
        hf8 b0f = *(const hf8*)&W[0][colA][off];
        hf8 b1f = *(const hf8*)&W[0][32 + colA][off];
        pe00 = mfma16(a0, b0f, pe00);
        pe01 = mfma16(a0, b1f, pe01);
        pe10 = mfma16(a1, b0f, pe10);
        pe11 = mfma16(a1, b1f, pe11);
    }
    __syncthreads();
#pragma unroll
    for (int r = 0; r < 16; ++r) {
        const int row = (r & 3) + 8*(r >> 2) + 4*(lane >> 5);
        X[32*p0 + row][colA]      = (_Float16)pe00[r];
        X[32*p0 + row][32 + colA] = (_Float16)pe01[r];
        X[32*p1 + row][colA]      = (_Float16)pe10[r];
        X[32*p1 + row][32 + colA] = (_Float16)pe11[r];
    }
    __syncthreads();

    // ---- GEMM2: h2 = pe @ aw1^T + ab1 ----
    f32x16 h00 = splat16(ab1[colA]);
    f32x16 h01 = splat16(ab1[32 + colA]);
    f32x16 h10 = h00, h11 = h01;
#pragma unroll
    for (int ks = 0; ks < 4; ++ks) {
        const int off = 16*ks + klo;
        hf8 a0  = *(const hf8*)&X[32*p0 + colA][off];
        hf8 a1  = *(const hf8*)&X[32*p1 + colA][off];
        hf8 b0f = *(const hf8*)&W[1][colA][off];
        hf8 b1f = *(const hf8*)&W[1][32 + colA][off];
        h00 = mfma16(a0, b0f, h00);
        h01 = mfma16(a0, b1f, h01);
        h10 = mfma16(a1, b0f, h10);
        h11 = mfma16(a1, b1f, h11);
    }
    __syncthreads();
    {
        const float a2l = cws[A2_OFF + (b << 6) + colA];
        const float a2h = cws[A2_OFF + (b << 6) + 32 + colA];
        const float c2l = cws[C2_OFF + (b << 6) + colA];
        const float c2h = cws[C2_OFF + (b << 6) + 32 + colA];
#pragma unroll
        for (int r = 0; r < 16; ++r) {
            const int row = (r & 3) + 8*(r >> 2) + 4*(lane >> 5);
            X[32*p0 + row][colA]      = (_Float16)fmaxf(fmaf(a2l, h00[r], c2l), 0.f);
            X[32*p0 + row][32 + colA] = (_Float16)fmaxf(fmaf(a2h, h01[r], c2h), 0.f);
            X[32*p1 + row][colA]      = (_Float16)fmaxf(fmaf(a2l, h10[r], c2l), 0.f);
            X[32*p1 + row][32 + colA] = (_Float16)fmaxf(fmaf(a2h, h11[r], c2h), 0.f);
        }
    }
    __syncthreads();

    // ---- GEMM3: logits = r2 @ aw2^T + ab2 ----
    f32x16 l00 = splat16(ab2[colA]);
    f32x16 l01 = splat16(ab2[32 + colA]);
    f32x16 l10 = l00, l11 = l01;
#pragma unroll
    for (int ks = 0; ks < 4; ++ks) {
        const int off = 16*ks + klo;
        hf8 a0  = *(const hf8*)&X[32*p0 + colA][off];
        hf8 a1  = *(const hf8*)&X[32*p1 + colA][off];
        hf8 b0f = *(const hf8*)&W[2][colA][off];
        hf8 b1f = *(const hf8*)&W[2][32 + colA][off];
        l00 = mfma16(a0, b0f, l00);
        l01 = mfma16(a0, b1f, l01);
        l10 = mfma16(a1, b0f, l10);
        l11 = mfma16(a1, b1f, l11);
    }

    // ---- masked softmax over K=16 (rows) + weighted pe sum ----
    auto softmax_tile = [&](const f32x16& lg, const f32x16& pe, int pp, int j) {
        const unsigned mb32 = (unsigned)(mbits >> (32*pp));
        const int rbase4 = 4*(lane >> 5);
#pragma unroll
        for (int mh = 0; mh < 2; ++mh) {
            float lv[8];
            float mx = NEG_BIG;
#pragma unroll
            for (int rr = 0; rr < 8; ++rr) {
                const int r = 8*mh + rr;
                const int row = (r & 3) + 8*(r >> 2) + rbase4;
                const float x = ((mb32 >> row) & 1u) ? lg[r] : NEG_BIG;
                lv[rr] = x;
                mx = fmaxf(mx, x);
            }
            mx = fmaxf(mx, __shfl_xor(mx, 32, 64));
            float se = 0.f, sw = 0.f;
#pragma unroll
            for (int rr = 0; rr < 8; ++rr) {
                const int r = 8*mh + rr;
                const float e = __expf(lv[rr] - mx);
                se += e;
                sw = fmaf(e, pe[r], sw);
            }
            se += __shfl_xor(se, 32, 64);
            sw += __shfl_xor(sw, 32, 64);
            if (lane < 32)
                O[32*j + lane][2*(2*wv + pp) + mh] = sw / se;
        }
    };
    softmax_tile(l00, pe00, 0, 0);
    softmax_tile(l01, pe01, 0, 1);
    softmax_tile(l10, pe10, 1, 0);
    softmax_tile(l11, pe11, 1, 1);
    __syncthreads();

    {
        const int o = tid >> 2;
        const int mq = (tid & 3) * 4;
        const int m0 = base >> 4;
        if (m0 + mq < Mn) {
            float4 v;
            v.x = O[o][mq]; v.y = O[o][mq + 1]; v.z = O[o][mq + 2]; v.w = O[o][mq + 3];
            *(float4*)&out[((size_t)b*64 + o)*Mn + m0 + mq] = v;
        }
    }
}

extern "C" void kernel_launch(void* const* d_in, const int* in_sizes, int n_in,
                              void* d_out, int out_size, void* d_ws, size_t ws_size,
                              hipStream_t stream) {
    (void)in_sizes; (void)n_in; (void)out_size; (void)ws_size;
    const float* q    = (const float*)d_in[0];
    const float* kx   = (const float*)d_in[1];
    const int*   idx  = (const int*)  d_in[2];
    const int*   mask = (const int*)  d_in[3];
    const float* w1   = (const float*)d_in[4];
    const float* b1   = (const float*)d_in[5];
    const float* g1   = (const float*)d_in[6];
    const float* be1  = (const float*)d_in[7];
    const float* w2   = (const float*)d_in[8];
    const float* b2   = (const float*)d_in[9];
    const float* aw1  = (const float*)d_in[10];
    const float* ab1  = (const float*)d_in[11];
    const float* g2   = (const float*)d_in[12];
    const float* be2  = (const float*)d_in[13];
    const float* aw2  = (const float*)d_in[14];
    const float* ab2  = (const float*)d_in[15];
    float* out = (float*)d_out;
    float* ws  = (float*)d_ws;

    hipMemsetAsync(ws, 0, WS_ZERO_FLOATS * sizeof(float), stream);

    stats1_kernel<<<dim3(128, Bn), 256, 0, stream>>>(q, kx, idx, ws);
    prep1_kernel<<<1, 256, 0, stream>>>(ws, w1, b1, g1, be1, w2, b2, aw1, ab1, ws);
    pass2_kernel<<<dim3(128, Bn), 256, 0, stream>>>(q, kx, idx, w1, b1, ws, ws);
    prep2_kernel<<<1, 128, 0, stream>>>(ws, g2, be2, ws);
    pass3_kernel<<<dim3((MK + 255) / 256, Bn), 256, 0, stream>>>(
        q, kx, idx, mask, w1, b1, w2, b2, aw1, ab1, aw2, ab2, ws, out);
}